// Round 1
// baseline (29215.295 us; speedup 1.0000x reference)
//
#include <hip/hip_runtime.h>

#define EMB 100
#define EMB4 25            // EMB/4 float4s per row
#define N_ITEMS 200000
#define BATCH 100
#define HIST_MAX 50
#define ITEM_ELEMS 20000000  // N_ITEMS * EMB

// ---------------- acc = gamma[0] * embedding ----------------
__global__ void k_init_acc(const float* __restrict__ emb,
                           const float* __restrict__ gamma,
                           float* __restrict__ acc, int n4) {
    int t = blockIdx.x * blockDim.x + threadIdx.x;
    if (t >= n4) return;
    float g = gamma[0];
    float4 v = ((const float4*)emb)[t];
    v.x *= g; v.y *= g; v.z *= g; v.w *= g;
    ((float4*)acc)[t] = v;
}

// ---------------- acc += item ----------------
__global__ void k_acc_add(float* __restrict__ acc,
                          const float* __restrict__ item, int n4) {
    int t = blockIdx.x * blockDim.x + threadIdx.x;
    if (t >= n4) return;
    float4 a = ((float4*)acc)[t];
    float4 b = ((const float4*)item)[t];
    a.x += b.x; a.y += b.y; a.z += b.z; a.w += b.w;
    ((float4*)acc)[t] = a;
}

// ---------------- COO SpMM scatter: out[row] += scale*val * x[col] ----------------
// 25 threads per nonzero; each thread handles one float4 (4 elems) of the row.
__global__ void k_spmm_atomic(const int* __restrict__ row,
                              const int* __restrict__ col,
                              const float* __restrict__ val,
                              const float* __restrict__ gamma, int gidx,
                              const float* __restrict__ x,
                              float* __restrict__ out, int nnz) {
    long long t = (long long)blockIdx.x * blockDim.x + threadIdx.x;
    long long total = (long long)nnz * EMB4;
    if (t >= total) return;
    int n = (int)(t / EMB4);
    int q = (int)(t % EMB4);
    int r = row[n];
    int c = col[n];
    float s = (gidx >= 0) ? gamma[gidx] : 1.0f;
    float v = val[n] * s;
    float4 xv = ((const float4*)x)[c * EMB4 + q];
    float* o = out + (long long)r * EMB + q * 4;
    atomicAdd(o + 0, v * xv.x);
    atomicAdd(o + 1, v * xv.y);
    atomicAdd(o + 2, v * xv.z);
    atomicAdd(o + 3, v * xv.w);
}

// ---------------- attention head: one block per batch element ----------------
__global__ void k_attn(const float* __restrict__ hist_emb,   // [B*H, EMB]
                       const int* __restrict__ hist_len,
                       const int* __restrict__ user,
                       const float* __restrict__ user_emb,   // [N_USERS, EMB]
                       const float* __restrict__ W1,         // [2*EMB]
                       float* __restrict__ out_user) {       // [B, EMB]
    __shared__ float w[2 * EMB];
    __shared__ float he[HIST_MAX * EMB];
    __shared__ float alpha[HIST_MAX];
    __shared__ float ued, mx, sm;
    int b = blockIdx.x;
    int tid = threadIdx.x;

    for (int i = tid; i < 2 * EMB; i += blockDim.x) w[i] = W1[i];
    for (int i = tid; i < HIST_MAX * EMB; i += blockDim.x)
        he[i] = hist_emb[(long long)b * HIST_MAX * EMB + i];
    __syncthreads();

    if (tid == 0) {
        const float* ue = user_emb + (long long)user[b] * EMB;
        float s = 0.f;
        for (int e = 0; e < EMB; e++) s += ue[e] * w[e];
        ued = s;
    }
    __syncthreads();

    int len = hist_len[b];
    if (tid < HIST_MAX) {
        float d = 0.f;
        for (int e = 0; e < EMB; e++) d += he[tid * EMB + e] * w[EMB + e];
        alpha[tid] = ued + d + (tid >= len ? -99999.0f : 0.0f);
    }
    __syncthreads();

    if (tid == 0) {
        float m = -1e30f;
        for (int h = 0; h < HIST_MAX; h++) m = fmaxf(m, alpha[h]);
        mx = m;
    }
    __syncthreads();
    if (tid < HIST_MAX) alpha[tid] = expf(alpha[tid] - mx);
    __syncthreads();
    if (tid == 0) {
        float s = 0.f;
        for (int h = 0; h < HIST_MAX; h++) s += alpha[h];
        sm = s;
    }
    __syncthreads();

    float denom = (len == 0) ? 1.0f : (float)len;
    if (tid < EMB) {
        float s = 0.f;
        for (int h = 0; h < HIST_MAX; h++) s += alpha[h] * he[h * EMB + tid];
        out_user[(long long)b * EMB + tid] = s / (sm * denom);
    }
}

extern "C" void kernel_launch(void* const* d_in, const int* in_sizes, int n_in,
                              void* d_out, int out_size, void* d_ws, size_t ws_size,
                              hipStream_t stream) {
    const int*   adj_row  = (const int*)d_in[0];
    const int*   adj_col  = (const int*)d_in[1];
    const float* adj_val  = (const float*)d_in[2];
    const int*   hist_row = (const int*)d_in[3];
    const int*   hist_col = (const int*)d_in[4];
    const float* hist_val = (const float*)d_in[5];
    const int*   hist_len = (const int*)d_in[6];
    const int*   user     = (const int*)d_in[7];
    const float* embedding      = (const float*)d_in[8];
    const float* user_embedding = (const float*)d_in[9];
    const float* gamma    = (const float*)d_in[10];
    const float* W1       = (const float*)d_in[11];

    float* acc      = (float*)d_out;            // item_embeddings [200000,100]
    float* user_out = acc + ITEM_ELEMS;         // [100,100]

    int nnzA = in_sizes[0];
    int nnzH = in_sizes[3];

    // workspace layout: buf1 (80MB) | buf2 (80MB) | hist_emb (2MB)
    char* ws = (char*)d_ws;
    float* buf1  = (float*)ws;
    float* buf2  = (float*)(ws + 80000000ULL);
    float* histe = (float*)(ws + 160000000ULL);

    hipMemsetAsync(buf1, 0, 80000000ULL, stream);
    hipMemsetAsync(buf2, 0, 80000000ULL, stream);
    hipMemsetAsync(histe, 0, (size_t)BATCH * HIST_MAX * EMB * sizeof(float), stream);

    const int n4 = ITEM_ELEMS / 4;
    k_init_acc<<<(n4 + 255) / 256, 256, 0, stream>>>(embedding, gamma, acc, n4);

    long long totA = (long long)nnzA * EMB4;
    int blocksA = (int)((totA + 255) / 256);

    // layer 1: buf1 = g1 * A @ embedding
    k_spmm_atomic<<<blocksA, 256, 0, stream>>>(adj_row, adj_col, adj_val, gamma, 1,
                                               embedding, buf1, nnzA);
    k_acc_add<<<(n4 + 255) / 256, 256, 0, stream>>>(acc, buf1, n4);

    // layer 2: buf2 = g2 * A @ buf1
    k_spmm_atomic<<<blocksA, 256, 0, stream>>>(adj_row, adj_col, adj_val, gamma, 2,
                                               buf1, buf2, nnzA);
    k_acc_add<<<(n4 + 255) / 256, 256, 0, stream>>>(acc, buf2, n4);

    // layer 3: acc += g3 * A @ buf2   (scatter directly into output accumulator)
    k_spmm_atomic<<<blocksA, 256, 0, stream>>>(adj_row, adj_col, adj_val, gamma, 3,
                                               buf2, acc, nnzA);

    // hist_emb = H @ item_embeddings  (tiny)
    long long totH = (long long)nnzH * EMB4;
    int blocksH = (int)((totH + 255) / 256);
    k_spmm_atomic<<<blocksH, 256, 0, stream>>>(hist_row, hist_col, hist_val, gamma, -1,
                                               acc, histe, nnzH);

    // attention head
    k_attn<<<BATCH, 128, 0, stream>>>(histe, hist_len, user, user_embedding, W1, user_out);
}

// Round 2
// 2655.519 us; speedup vs baseline: 11.0017x; 11.0017x over previous
//
#include <hip/hip_runtime.h>

#define EMB 100
#define EMB4 25            // EMB/4 float4s per row
#define N_ITEMS 200000
#define BATCH 100
#define HIST_MAX 50
#define ITEM_ELEMS 20000000  // N_ITEMS * EMB

// ================= CSR build =================

__global__ void k_histogram(const int* __restrict__ row, int* __restrict__ cnt, int nnz) {
    int i = blockIdx.x * blockDim.x + threadIdx.x;
    if (i < nnz) atomicAdd(&cnt[row[i]], 1);
}

// single-block exclusive scan: rowptr[0]=0; rowptr[i+1]=sum(cnt[0..i])
__global__ void k_scan(const int* __restrict__ cnt, int* __restrict__ rowptr, int n) {
    __shared__ int sdata[1024];
    __shared__ int running;
    int tid = threadIdx.x;
    if (tid == 0) { running = 0; rowptr[0] = 0; }
    __syncthreads();
    for (int base = 0; base < n; base += 1024) {
        int i = base + tid;
        int v = (i < n) ? cnt[i] : 0;
        sdata[tid] = v;
        __syncthreads();
        for (int off = 1; off < 1024; off <<= 1) {
            int t2 = (tid >= off) ? sdata[tid - off] : 0;
            __syncthreads();
            sdata[tid] += t2;
            __syncthreads();
        }
        int incl = sdata[tid];
        if (i < n) rowptr[i + 1] = running + incl;
        __syncthreads();
        if (tid == 1023) running += sdata[1023];
        __syncthreads();
    }
}

__global__ void k_copyptr(const int* __restrict__ rowptr, int* __restrict__ fillpos, int n) {
    int i = blockIdx.x * blockDim.x + threadIdx.x;
    if (i < n) fillpos[i] = rowptr[i];
}

__global__ void k_fill(const int* __restrict__ row, const int* __restrict__ col,
                       const float* __restrict__ val, int* __restrict__ fillpos,
                       int* __restrict__ colp, float* __restrict__ valp, int nnz) {
    int i = blockIdx.x * blockDim.x + threadIdx.x;
    if (i >= nnz) return;
    int r = row[i];
    int pos = atomicAdd(&fillpos[r], 1);
    colp[pos] = col[i];
    valp[pos] = val[i];
}

// ================= gather SpMM =================
// thread t -> (row r = t/25, float4 slot = t%25). No atomics.
// emb!=null => final mode: acc = g0*emb + b1 + b2 + g[gidx]*sum
// else: out = g[gidx]*sum
__global__ void k_spmm_gather(const int* __restrict__ rowptr, const int* __restrict__ colp,
                              const float* __restrict__ valp, const float* __restrict__ x,
                              const float* __restrict__ gamma, int gidx,
                              float* __restrict__ out,
                              const float* __restrict__ emb,
                              const float* __restrict__ b1, const float* __restrict__ b2,
                              float* __restrict__ acc) {
    int t = blockIdx.x * blockDim.x + threadIdx.x;
    if (t >= N_ITEMS * EMB4) return;
    int r = t / EMB4;
    int slot = t - r * EMB4;
    int j0 = rowptr[r], j1 = rowptr[r + 1];
    const float4* x4 = (const float4*)x;
    float4 s = make_float4(0.f, 0.f, 0.f, 0.f);
    for (int j = j0; j < j1; ++j) {
        int c = colp[j];
        float v = valp[j];
        float4 xv = x4[c * EMB4 + slot];
        s.x += v * xv.x; s.y += v * xv.y; s.z += v * xv.z; s.w += v * xv.w;
    }
    float g = gamma[gidx];
    s.x *= g; s.y *= g; s.z *= g; s.w *= g;
    if (emb) {
        float g0 = gamma[0];
        float4 e  = ((const float4*)emb)[t];
        float4 a1 = ((const float4*)b1)[t];
        float4 a2 = ((const float4*)b2)[t];
        s.x += g0 * e.x + a1.x + a2.x;
        s.y += g0 * e.y + a1.y + a2.y;
        s.z += g0 * e.z + a1.z + a2.z;
        s.w += g0 * e.w + a1.w + a2.w;
        ((float4*)acc)[t] = s;
    } else {
        ((float4*)out)[t] = s;
    }
}

// ================= fallback atomic path (also used for tiny hist SpMM) =================

__global__ void k_init_acc(const float* __restrict__ emb,
                           const float* __restrict__ gamma,
                           float* __restrict__ acc, int n4) {
    int t = blockIdx.x * blockDim.x + threadIdx.x;
    if (t >= n4) return;
    float g = gamma[0];
    float4 v = ((const float4*)emb)[t];
    v.x *= g; v.y *= g; v.z *= g; v.w *= g;
    ((float4*)acc)[t] = v;
}

__global__ void k_acc_add(float* __restrict__ acc,
                          const float* __restrict__ item, int n4) {
    int t = blockIdx.x * blockDim.x + threadIdx.x;
    if (t >= n4) return;
    float4 a = ((float4*)acc)[t];
    float4 b = ((const float4*)item)[t];
    a.x += b.x; a.y += b.y; a.z += b.z; a.w += b.w;
    ((float4*)acc)[t] = a;
}

__global__ void k_spmm_atomic(const int* __restrict__ row,
                              const int* __restrict__ col,
                              const float* __restrict__ val,
                              const float* __restrict__ gamma, int gidx,
                              const float* __restrict__ x,
                              float* __restrict__ out, int nnz) {
    long long t = (long long)blockIdx.x * blockDim.x + threadIdx.x;
    long long total = (long long)nnz * EMB4;
    if (t >= total) return;
    int n = (int)(t / EMB4);
    int q = (int)(t % EMB4);
    int r = row[n];
    int c = col[n];
    float s = (gidx >= 0) ? gamma[gidx] : 1.0f;
    float v = val[n] * s;
    float4 xv = ((const float4*)x)[c * EMB4 + q];
    float* o = out + (long long)r * EMB + q * 4;
    atomicAdd(o + 0, v * xv.x);
    atomicAdd(o + 1, v * xv.y);
    atomicAdd(o + 2, v * xv.z);
    atomicAdd(o + 3, v * xv.w);
}

// ================= attention head =================
__global__ void k_attn(const float* __restrict__ hist_emb,   // [B*H, EMB]
                       const int* __restrict__ hist_len,
                       const int* __restrict__ user,
                       const float* __restrict__ user_emb,   // [N_USERS, EMB]
                       const float* __restrict__ W1,         // [2*EMB]
                       float* __restrict__ out_user) {       // [B, EMB]
    __shared__ float w[2 * EMB];
    __shared__ float he[HIST_MAX * EMB];
    __shared__ float alpha[HIST_MAX];
    __shared__ float ued, mx, sm;
    int b = blockIdx.x;
    int tid = threadIdx.x;

    for (int i = tid; i < 2 * EMB; i += blockDim.x) w[i] = W1[i];
    for (int i = tid; i < HIST_MAX * EMB; i += blockDim.x)
        he[i] = hist_emb[(long long)b * HIST_MAX * EMB + i];
    __syncthreads();

    if (tid == 0) {
        const float* ue = user_emb + (long long)user[b] * EMB;
        float s = 0.f;
        for (int e = 0; e < EMB; e++) s += ue[e] * w[e];
        ued = s;
    }
    __syncthreads();

    int len = hist_len[b];
    if (tid < HIST_MAX) {
        float d = 0.f;
        for (int e = 0; e < EMB; e++) d += he[tid * EMB + e] * w[EMB + e];
        alpha[tid] = ued + d + (tid >= len ? -99999.0f : 0.0f);
    }
    __syncthreads();

    if (tid == 0) {
        float m = -1e30f;
        for (int h = 0; h < HIST_MAX; h++) m = fmaxf(m, alpha[h]);
        mx = m;
    }
    __syncthreads();
    if (tid < HIST_MAX) alpha[tid] = expf(alpha[tid] - mx);
    __syncthreads();
    if (tid == 0) {
        float s = 0.f;
        for (int h = 0; h < HIST_MAX; h++) s += alpha[h];
        sm = s;
    }
    __syncthreads();

    float denom = (len == 0) ? 1.0f : (float)len;
    if (tid < EMB) {
        float s = 0.f;
        for (int h = 0; h < HIST_MAX; h++) s += alpha[h] * he[h * EMB + tid];
        out_user[(long long)b * EMB + tid] = s / (sm * denom);
    }
}

extern "C" void kernel_launch(void* const* d_in, const int* in_sizes, int n_in,
                              void* d_out, int out_size, void* d_ws, size_t ws_size,
                              hipStream_t stream) {
    const int*   adj_row  = (const int*)d_in[0];
    const int*   adj_col  = (const int*)d_in[1];
    const float* adj_val  = (const float*)d_in[2];
    const int*   hist_row = (const int*)d_in[3];
    const int*   hist_col = (const int*)d_in[4];
    const float* hist_val = (const float*)d_in[5];
    const int*   hist_len = (const int*)d_in[6];
    const int*   user     = (const int*)d_in[7];
    const float* embedding      = (const float*)d_in[8];
    const float* user_embedding = (const float*)d_in[9];
    const float* gamma    = (const float*)d_in[10];
    const float* W1       = (const float*)d_in[11];

    float* acc      = (float*)d_out;            // item_embeddings [200000,100]
    float* user_out = acc + ITEM_ELEMS;         // [100,100]

    int nnzA = in_sizes[0];
    int nnzH = in_sizes[3];

    // workspace layout
    char* ws = (char*)d_ws;
    size_t off = 0;
    float* buf1 = (float*)(ws + off);   off += 80000000ULL;            // item layer buf
    float* buf2 = (float*)(ws + off);   off += 80000000ULL;            // item layer buf
    int*   colp = (int*)(ws + off);     off += (size_t)nnzA * 4;       // CSR cols
    float* valp = (float*)(ws + off);   off += (size_t)nnzA * 4;       // CSR vals
    int*   rowptr = (int*)(ws + off);   off += ((size_t)N_ITEMS + 4) * 4;
    int*   cnt  = (int*)(ws + off);     off += (size_t)N_ITEMS * 4;    // histogram / fillpos
    float* histe = (float*)(ws + off);  off += (size_t)BATCH * HIST_MAX * EMB * 4;
    size_t need_csr = off;

    const int n4 = ITEM_ELEMS / 4;
    long long totH = (long long)nnzH * EMB4;
    int blocksH = (int)((totH + 255) / 256);

    if (ws_size >= need_csr) {
        // ---------- CSR gather path ----------
        hipMemsetAsync(cnt, 0, (size_t)N_ITEMS * 4, stream);
        hipMemsetAsync(histe, 0, (size_t)BATCH * HIST_MAX * EMB * 4, stream);

        int bN = (nnzA + 255) / 256;
        k_histogram<<<bN, 256, 0, stream>>>(adj_row, cnt, nnzA);
        k_scan<<<1, 1024, 0, stream>>>(cnt, rowptr, N_ITEMS);
        k_copyptr<<<(N_ITEMS + 255) / 256, 256, 0, stream>>>(rowptr, cnt, N_ITEMS);
        k_fill<<<bN, 256, 0, stream>>>(adj_row, adj_col, adj_val, cnt, colp, valp, nnzA);

        int gThreads = N_ITEMS * EMB4;
        int gBlocks = (gThreads + 255) / 256;
        // layer 1: buf1 = g1 * A @ embedding
        k_spmm_gather<<<gBlocks, 256, 0, stream>>>(rowptr, colp, valp, embedding, gamma, 1,
                                                   buf1, nullptr, nullptr, nullptr, nullptr);
        // layer 2: buf2 = g2 * A @ buf1
        k_spmm_gather<<<gBlocks, 256, 0, stream>>>(rowptr, colp, valp, buf1, gamma, 2,
                                                   buf2, nullptr, nullptr, nullptr, nullptr);
        // layer 3 + fused epilogue: acc = g0*emb + buf1 + buf2 + g3 * A @ buf2
        k_spmm_gather<<<gBlocks, 256, 0, stream>>>(rowptr, colp, valp, buf2, gamma, 3,
                                                   nullptr, embedding, buf1, buf2, acc);
    } else {
        // ---------- fallback atomic path ----------
        hipMemsetAsync(buf1, 0, 80000000ULL, stream);
        hipMemsetAsync(buf2, 0, 80000000ULL, stream);
        hipMemsetAsync(histe, 0, (size_t)BATCH * HIST_MAX * EMB * 4, stream);

        k_init_acc<<<(n4 + 255) / 256, 256, 0, stream>>>(embedding, gamma, acc, n4);
        long long totA = (long long)nnzA * EMB4;
        int blocksA = (int)((totA + 255) / 256);
        k_spmm_atomic<<<blocksA, 256, 0, stream>>>(adj_row, adj_col, adj_val, gamma, 1,
                                                   embedding, buf1, nnzA);
        k_acc_add<<<(n4 + 255) / 256, 256, 0, stream>>>(acc, buf1, n4);
        k_spmm_atomic<<<blocksA, 256, 0, stream>>>(adj_row, adj_col, adj_val, gamma, 2,
                                                   buf1, buf2, nnzA);
        k_acc_add<<<(n4 + 255) / 256, 256, 0, stream>>>(acc, buf2, n4);
        k_spmm_atomic<<<blocksA, 256, 0, stream>>>(adj_row, adj_col, adj_val, gamma, 3,
                                                   buf2, acc, nnzA);
    }

    // hist_emb = H @ item_embeddings (tiny, atomic scatter is fine)
    k_spmm_atomic<<<blocksH, 256, 0, stream>>>(hist_row, hist_col, hist_val, gamma, -1,
                                               acc, histe, nnzH);

    // attention head
    k_attn<<<BATCH, 128, 0, stream>>>(histe, hist_len, user, user_embedding, W1, user_out);
}

// Round 3
// 2229.603 us; speedup vs baseline: 13.1034x; 1.1910x over previous
//
#include <hip/hip_runtime.h>

#define EMB 100
#define EMB4 25            // EMB/4 float4s per row
#define N_ITEMS 200000
#define BATCH 100
#define HIST_MAX 50
#define ITEM_ELEMS 20000000  // N_ITEMS * EMB
#define SCAN_B 1024
#define NSCAN_BLOCKS ((N_ITEMS + SCAN_B - 1) / SCAN_B)   // 196 (< 256)

// ================= CSR build =================

__global__ void k_histogram(const int* __restrict__ row, int* __restrict__ cnt, int nnz) {
    int i = blockIdx.x * blockDim.x + threadIdx.x;
    if (i < nnz) atomicAdd(&cnt[row[i]], 1);
}

// per-block inclusive scan; writes rowptr[i+1] (pre-offset) and block sum
__global__ void k_scan_local(const int* __restrict__ cnt, int* __restrict__ rowptr,
                             int* __restrict__ blocksum, int n) {
    __shared__ int sd[SCAN_B];
    int b = blockIdx.x, tid = threadIdx.x;
    int i = b * SCAN_B + tid;
    int v = (i < n) ? cnt[i] : 0;
    sd[tid] = v;
    __syncthreads();
    for (int off = 1; off < SCAN_B; off <<= 1) {
        int t = (tid >= off) ? sd[tid - off] : 0;
        __syncthreads();
        sd[tid] += t;
        __syncthreads();
    }
    if (i < n) rowptr[i + 1] = sd[tid];
    if (tid == SCAN_B - 1) blocksum[b] = sd[tid];
}

// single block: exclusive scan of <=256 block sums in place
__global__ void k_scan_blocks(int* __restrict__ blocksum, int nb) {
    __shared__ int sd[256];
    int tid = threadIdx.x;
    int v = (tid < nb) ? blocksum[tid] : 0;
    sd[tid] = v;
    __syncthreads();
    for (int off = 1; off < 256; off <<= 1) {
        int t = (tid >= off) ? sd[tid - off] : 0;
        __syncthreads();
        sd[tid] += t;
        __syncthreads();
    }
    if (tid < nb) blocksum[tid] = sd[tid] - v;  // exclusive
}

__global__ void k_scan_add(int* __restrict__ rowptr, const int* __restrict__ blocksum, int n) {
    int i = blockIdx.x * blockDim.x + threadIdx.x;
    if (i == 0) rowptr[0] = 0;
    if (i < n) rowptr[i + 1] += blocksum[i / SCAN_B];
}

// fill CSR using atomicSub on cnt (row length) -> no fillpos copy needed.
// stores packed (col, val) as int2 -> single 8B scattered store.
__global__ void k_fill(const int* __restrict__ row, const int* __restrict__ col,
                       const float* __restrict__ val, const int* __restrict__ rowptr,
                       int* __restrict__ cnt, int2* __restrict__ cvp, int nnz) {
    int i = blockIdx.x * blockDim.x + threadIdx.x;
    if (i >= nnz) return;
    int r = row[i];
    int old = atomicSub(&cnt[r], 1);        // old in [1..len]
    int pos = rowptr[r] + old - 1;
    cvp[pos] = make_int2(col[i], __float_as_int(val[i]));
}

// ================= gather SpMM =================
// thread t -> (row r = t/25, float4 slot = t%25). No atomics.
// emb!=null => final mode: acc = g0*emb + b1 + b2 + g[gidx]*sum
__global__ void k_spmm_gather(const int* __restrict__ rowptr, const int2* __restrict__ cvp,
                              const float* __restrict__ x,
                              const float* __restrict__ gamma, int gidx,
                              float* __restrict__ out,
                              const float* __restrict__ emb,
                              const float* __restrict__ b1, const float* __restrict__ b2,
                              float* __restrict__ acc) {
    int t = blockIdx.x * blockDim.x + threadIdx.x;
    if (t >= N_ITEMS * EMB4) return;
    int r = t / EMB4;
    int slot = t - r * EMB4;
    int j0 = rowptr[r], j1 = rowptr[r + 1];
    const float4* x4 = (const float4*)x;
    float4 s = make_float4(0.f, 0.f, 0.f, 0.f);
    int j = j0;
    // 4-wide manual unroll: 4 cv loads then 4 independent gathers in flight
    for (; j + 4 <= j1; j += 4) {
        int2 c0 = cvp[j + 0];
        int2 c1 = cvp[j + 1];
        int2 c2 = cvp[j + 2];
        int2 c3 = cvp[j + 3];
        float4 v0 = x4[c0.x * EMB4 + slot];
        float4 v1 = x4[c1.x * EMB4 + slot];
        float4 v2 = x4[c2.x * EMB4 + slot];
        float4 v3 = x4[c3.x * EMB4 + slot];
        float f0 = __int_as_float(c0.y), f1 = __int_as_float(c1.y);
        float f2 = __int_as_float(c2.y), f3 = __int_as_float(c3.y);
        s.x += f0 * v0.x + f1 * v1.x + f2 * v2.x + f3 * v3.x;
        s.y += f0 * v0.y + f1 * v1.y + f2 * v2.y + f3 * v3.y;
        s.z += f0 * v0.z + f1 * v1.z + f2 * v2.z + f3 * v3.z;
        s.w += f0 * v0.w + f1 * v1.w + f2 * v2.w + f3 * v3.w;
    }
    for (; j < j1; ++j) {
        int2 c = cvp[j];
        float4 v = x4[c.x * EMB4 + slot];
        float f = __int_as_float(c.y);
        s.x += f * v.x; s.y += f * v.y; s.z += f * v.z; s.w += f * v.w;
    }
    float g = gamma[gidx];
    s.x *= g; s.y *= g; s.z *= g; s.w *= g;
    if (emb) {
        float g0 = gamma[0];
        float4 e  = ((const float4*)emb)[t];
        float4 a1 = ((const float4*)b1)[t];
        float4 a2 = ((const float4*)b2)[t];
        s.x += g0 * e.x + a1.x + a2.x;
        s.y += g0 * e.y + a1.y + a2.y;
        s.z += g0 * e.z + a1.z + a2.z;
        s.w += g0 * e.w + a1.w + a2.w;
        ((float4*)acc)[t] = s;
    } else {
        ((float4*)out)[t] = s;
    }
}

// ================= fallback atomic path (also used for tiny hist SpMM) =================

__global__ void k_init_acc(const float* __restrict__ emb,
                           const float* __restrict__ gamma,
                           float* __restrict__ acc, int n4) {
    int t = blockIdx.x * blockDim.x + threadIdx.x;
    if (t >= n4) return;
    float g = gamma[0];
    float4 v = ((const float4*)emb)[t];
    v.x *= g; v.y *= g; v.z *= g; v.w *= g;
    ((float4*)acc)[t] = v;
}

__global__ void k_acc_add(float* __restrict__ acc,
                          const float* __restrict__ item, int n4) {
    int t = blockIdx.x * blockDim.x + threadIdx.x;
    if (t >= n4) return;
    float4 a = ((float4*)acc)[t];
    float4 b = ((const float4*)item)[t];
    a.x += b.x; a.y += b.y; a.z += b.z; a.w += b.w;
    ((float4*)acc)[t] = a;
}

__global__ void k_spmm_atomic(const int* __restrict__ row,
                              const int* __restrict__ col,
                              const float* __restrict__ val,
                              const float* __restrict__ gamma, int gidx,
                              const float* __restrict__ x,
                              float* __restrict__ out, int nnz) {
    long long t = (long long)blockIdx.x * blockDim.x + threadIdx.x;
    long long total = (long long)nnz * EMB4;
    if (t >= total) return;
    int n = (int)(t / EMB4);
    int q = (int)(t % EMB4);
    int r = row[n];
    int c = col[n];
    float s = (gidx >= 0) ? gamma[gidx] : 1.0f;
    float v = val[n] * s;
    float4 xv = ((const float4*)x)[c * EMB4 + q];
    float* o = out + (long long)r * EMB + q * 4;
    atomicAdd(o + 0, v * xv.x);
    atomicAdd(o + 1, v * xv.y);
    atomicAdd(o + 2, v * xv.z);
    atomicAdd(o + 3, v * xv.w);
}

// ================= attention head =================
__global__ void k_attn(const float* __restrict__ hist_emb,   // [B*H, EMB]
                       const int* __restrict__ hist_len,
                       const int* __restrict__ user,
                       const float* __restrict__ user_emb,   // [N_USERS, EMB]
                       const float* __restrict__ W1,         // [2*EMB]
                       float* __restrict__ out_user) {       // [B, EMB]
    __shared__ float w[2 * EMB];
    __shared__ float he[HIST_MAX * EMB];
    __shared__ float alpha[HIST_MAX];
    __shared__ float ued, mx, sm;
    int b = blockIdx.x;
    int tid = threadIdx.x;

    for (int i = tid; i < 2 * EMB; i += blockDim.x) w[i] = W1[i];
    for (int i = tid; i < HIST_MAX * EMB; i += blockDim.x)
        he[i] = hist_emb[(long long)b * HIST_MAX * EMB + i];
    __syncthreads();

    if (tid == 0) {
        const float* ue = user_emb + (long long)user[b] * EMB;
        float s = 0.f;
        for (int e = 0; e < EMB; e++) s += ue[e] * w[e];
        ued = s;
    }
    __syncthreads();

    int len = hist_len[b];
    if (tid < HIST_MAX) {
        float d = 0.f;
        for (int e = 0; e < EMB; e++) d += he[tid * EMB + e] * w[EMB + e];
        alpha[tid] = ued + d + (tid >= len ? -99999.0f : 0.0f);
    }
    __syncthreads();

    if (tid == 0) {
        float m = -1e30f;
        for (int h = 0; h < HIST_MAX; h++) m = fmaxf(m, alpha[h]);
        mx = m;
    }
    __syncthreads();
    if (tid < HIST_MAX) alpha[tid] = expf(alpha[tid] - mx);
    __syncthreads();
    if (tid == 0) {
        float s = 0.f;
        for (int h = 0; h < HIST_MAX; h++) s += alpha[h];
        sm = s;
    }
    __syncthreads();

    float denom = (len == 0) ? 1.0f : (float)len;
    if (tid < EMB) {
        float s = 0.f;
        for (int h = 0; h < HIST_MAX; h++) s += alpha[h] * he[h * EMB + tid];
        out_user[(long long)b * EMB + tid] = s / (sm * denom);
    }
}

extern "C" void kernel_launch(void* const* d_in, const int* in_sizes, int n_in,
                              void* d_out, int out_size, void* d_ws, size_t ws_size,
                              hipStream_t stream) {
    const int*   adj_row  = (const int*)d_in[0];
    const int*   adj_col  = (const int*)d_in[1];
    const float* adj_val  = (const float*)d_in[2];
    const int*   hist_row = (const int*)d_in[3];
    const int*   hist_col = (const int*)d_in[4];
    const float* hist_val = (const float*)d_in[5];
    const int*   hist_len = (const int*)d_in[6];
    const int*   user     = (const int*)d_in[7];
    const float* embedding      = (const float*)d_in[8];
    const float* user_embedding = (const float*)d_in[9];
    const float* gamma    = (const float*)d_in[10];
    const float* W1       = (const float*)d_in[11];

    float* acc      = (float*)d_out;            // item_embeddings [200000,100]
    float* user_out = acc + ITEM_ELEMS;         // [100,100]

    int nnzA = in_sizes[0];
    int nnzH = in_sizes[3];

    // workspace layout
    char* ws = (char*)d_ws;
    size_t off = 0;
    float* buf1 = (float*)(ws + off);     off += 80000000ULL;
    float* buf2 = (float*)(ws + off);     off += 80000000ULL;
    int2*  cvp  = (int2*)(ws + off);      off += (size_t)nnzA * 8;        // packed CSR (col,val)
    int*   rowptr = (int*)(ws + off);     off += ((size_t)N_ITEMS + 4) * 4;
    int*   cnt  = (int*)(ws + off);       off += (size_t)N_ITEMS * 4;
    int*   blocksum = (int*)(ws + off);   off += 256 * 4;
    float* histe = (float*)(ws + off);    off += (size_t)BATCH * HIST_MAX * EMB * 4;
    size_t need_csr = off;

    const int n4 = ITEM_ELEMS / 4;
    long long totH = (long long)nnzH * EMB4;
    int blocksH = (int)((totH + 255) / 256);

    if (ws_size >= need_csr) {
        // ---------- CSR gather path ----------
        hipMemsetAsync(cnt, 0, (size_t)N_ITEMS * 4, stream);
        hipMemsetAsync(histe, 0, (size_t)BATCH * HIST_MAX * EMB * 4, stream);

        int bN = (nnzA + 255) / 256;
        k_histogram<<<bN, 256, 0, stream>>>(adj_row, cnt, nnzA);
        k_scan_local<<<NSCAN_BLOCKS, SCAN_B, 0, stream>>>(cnt, rowptr, blocksum, N_ITEMS);
        k_scan_blocks<<<1, 256, 0, stream>>>(blocksum, NSCAN_BLOCKS);
        k_scan_add<<<(N_ITEMS + 255) / 256, 256, 0, stream>>>(rowptr, blocksum, N_ITEMS);
        k_fill<<<bN, 256, 0, stream>>>(adj_row, adj_col, adj_val, rowptr, cnt, cvp, nnzA);

        int gThreads = N_ITEMS * EMB4;
        int gBlocks = (gThreads + 255) / 256;
        // layer 1: buf1 = g1 * A @ embedding
        k_spmm_gather<<<gBlocks, 256, 0, stream>>>(rowptr, cvp, embedding, gamma, 1,
                                                   buf1, nullptr, nullptr, nullptr, nullptr);
        // layer 2: buf2 = g2 * A @ buf1
        k_spmm_gather<<<gBlocks, 256, 0, stream>>>(rowptr, cvp, buf1, gamma, 2,
                                                   buf2, nullptr, nullptr, nullptr, nullptr);
        // layer 3 + fused epilogue: acc = g0*emb + buf1 + buf2 + g3 * A @ buf2
        k_spmm_gather<<<gBlocks, 256, 0, stream>>>(rowptr, cvp, buf2, gamma, 3,
                                                   nullptr, embedding, buf1, buf2, acc);
    } else {
        // ---------- fallback atomic path ----------
        hipMemsetAsync(buf1, 0, 80000000ULL, stream);
        hipMemsetAsync(buf2, 0, 80000000ULL, stream);
        hipMemsetAsync(histe, 0, (size_t)BATCH * HIST_MAX * EMB * 4, stream);

        k_init_acc<<<(n4 + 255) / 256, 256, 0, stream>>>(embedding, gamma, acc, n4);
        long long totA = (long long)nnzA * EMB4;
        int blocksA = (int)((totA + 255) / 256);
        k_spmm_atomic<<<blocksA, 256, 0, stream>>>(adj_row, adj_col, adj_val, gamma, 1,
                                                   embedding, buf1, nnzA);
        k_acc_add<<<(n4 + 255) / 256, 256, 0, stream>>>(acc, buf1, n4);
        k_spmm_atomic<<<blocksA, 256, 0, stream>>>(adj_row, adj_col, adj_val, gamma, 2,
                                                   buf1, buf2, nnzA);
        k_acc_add<<<(n4 + 255) / 256, 256, 0, stream>>>(acc, buf2, n4);
        k_spmm_atomic<<<blocksA, 256, 0, stream>>>(adj_row, adj_col, adj_val, gamma, 3,
                                                   buf2, acc, nnzA);
    }

    // hist_emb = H @ item_embeddings (tiny, atomic scatter is fine)
    k_spmm_atomic<<<blocksH, 256, 0, stream>>>(hist_row, hist_col, hist_val, gamma, -1,
                                               acc, histe, nnzH);

    // attention head
    k_attn<<<BATCH, 128, 0, stream>>>(histe, hist_len, user, user_embedding, W1, user_out);
}